// Round 3
// baseline (425.237 us; speedup 1.0000x reference)
//
#include <hip/hip_runtime.h>
#include <stdint.h>

#define T_SEQ 2048
#define NH 16
#define HD 128
#define CC 2048
#define N3 6144
#define MM 4096   // B*T

typedef short bf16x8 __attribute__((ext_vector_type(8)));
typedef float f32x4 __attribute__((ext_vector_type(4)));

__device__ __forceinline__ unsigned short f2bf(float f) {
  unsigned int u = __float_as_uint(f);
  u += 0x7FFF + ((u >> 16) & 1);   // RNE
  return (unsigned short)(u >> 16);
}
__device__ __forceinline__ float bf2f(unsigned short h) {
  return __uint_as_float(((unsigned int)h) << 16);
}

// ---------------- transpose + fp32->bf16 convert: out[n][k] = in[k][n] ----------------
__global__ __launch_bounds__(256) void k_transpose_cvt(const float* __restrict__ in,
                                                       unsigned short* __restrict__ out,
                                                       int K, int N) {
  __shared__ float tile[32][33];
  int k0 = blockIdx.x * 32;
  int n0 = blockIdx.y * 32;
  int tx = threadIdx.x & 31, ty = threadIdx.x >> 5;   // ty 0..7
  #pragma unroll
  for (int r = ty; r < 32; r += 8)
    tile[r][tx] = in[(size_t)(k0 + r) * N + n0 + tx];
  __syncthreads();
  #pragma unroll
  for (int r = ty; r < 32; r += 8)
    out[(size_t)(n0 + r) * K + k0 + tx] = f2bf(tile[tx][r]);
}

// ---------------- fp32 -> bf16 elementwise (x) ----------------
__global__ __launch_bounds__(256) void k_cvt(const float* __restrict__ in,
                                             unsigned short* __restrict__ out, int n4) {
  int i = blockIdx.x * 256 + threadIdx.x;
  if (i >= n4) return;
  float4 v = ((const float4*)in)[i];
  ushort4 o;
  o.x = f2bf(v.x); o.y = f2bf(v.y); o.z = f2bf(v.z); o.w = f2bf(v.w);
  ((ushort4*)out)[i] = o;
}

// ---------------- bf16 GEMM, 256x256 8-phase template: C = A[M,K] * Bt[N,K]^T ------------
// 512 threads = 8 waves (2 M x 4 N). BK=64, 2 K-tiles per iteration, 128KB LDS.
// LDS: region(d,op,h) 16KB each: [dbuf][A/B][half 128 rows][64 k] bf16, st_16x32 swizzle.
// EPI==0: fp32 C.  EPI==1: scatter bf16 into q/k/v (B,H,T,D).
template<int EPI>
__global__ __launch_bounds__(512, 2) void k_gemm8(const unsigned short* __restrict__ A,
                                                  const unsigned short* __restrict__ Bt,
                                                  float* __restrict__ C,
                                                  unsigned short* __restrict__ qo,
                                                  unsigned short* __restrict__ ko,
                                                  unsigned short* __restrict__ vo,
                                                  int M, int N, int K) {
  extern __shared__ __align__(16) char lds[];   // 131072 bytes
  const int tid = threadIdx.x;
  const int lane = tid & 63;
  const int lr = lane & 15, lg = lane >> 4;
  const int wave = tid >> 6;
  const int wm = wave >> 2, wn = wave & 3;
  const int m0 = blockIdx.x * 256, n0 = blockIdx.y * 256;
  const int NT = K >> 6;

  // stage one half-tile (128 rows x 64 k) of tile t into region (d,op,h).
  // LDS dest linear; global source pre-swizzled with st_16x32 (byte ^= ((byte>>9)&1)<<5).
  auto STAGE = [&](int d, int op, int h, int t) {
    const unsigned short* src = op ? Bt : A;
    const int r0 = (op ? n0 : m0) + h * 128;
    const int kc = t * 64;
    char* base = lds + ((((d << 1) | op) << 1 | h) << 14);
    #pragma unroll
    for (int l = 0; l < 2; ++l) {
      int p = (l * 512 + tid) * 16;
      int q = p ^ (((p >> 9) & 1) << 5);
      const unsigned short* g = src + (size_t)(r0 + (q >> 7)) * K + kc + ((q & 127) >> 1);
      __builtin_amdgcn_global_load_lds(
          (const __attribute__((address_space(1))) void*)g,
          (__attribute__((address_space(3))) void*)(base + (l * 512 + (tid & 448)) * 16),
          16, 0, 0);
    }
  };
  // swizzled fragment read: row in [0,128), kb = byte col in [0,128)
  auto RD = [&](int d, int op, int h, int row, int kb) -> bf16x8 {
    const char* base = lds + ((((d << 1) | op) << 1 | h) << 14);
    int p = row * 128 + kb;
    p ^= ((p >> 9) & 1) << 5;
    return *(const bf16x8*)(base + p);
  };

  f32x4 acc[8][4];
  #pragma unroll
  for (int i = 0; i < 8; ++i)
    #pragma unroll
    for (int j = 0; j < 4; ++j) acc[i][j] = (f32x4){0.f, 0.f, 0.f, 0.f};

  // prologue: tile0 -> d0 (4 HT), tile1 A-halves -> d1 (2 HT)
  STAGE(0, 0, 0, 0); STAGE(0, 0, 1, 0); STAGE(0, 1, 0, 0); STAGE(0, 1, 1, 0);
  STAGE(1, 0, 0, 1); STAGE(1, 0, 1, 1);
  asm volatile("s_waitcnt vmcnt(4)" ::: "memory");   // tile0 fully landed
  __builtin_amdgcn_s_barrier();

  bf16x8 afrg[8][2], bfrg[4][2];
  const int brow = (wn & 1) * 64;

  for (int it = 0; it < (NT >> 1); ++it) {
    const int tb = 2 * it + 1;
    const int tn0 = min(2 * it + 2, NT - 1);
    const int tn1 = min(2 * it + 3, NT - 1);

    // ================= K-tile a = 2*it, dbuf 0 =================
    // ph1: all B frags + A q1; stage b.BH0 -> d1
    #pragma unroll
    for (int nj = 0; nj < 4; ++nj)
      #pragma unroll
      for (int ks = 0; ks < 2; ++ks)
        bfrg[nj][ks] = RD(0, 1, wn >> 1, brow + nj * 16 + lr, ks * 64 + lg * 16);
    #pragma unroll
    for (int mi = 0; mi < 2; ++mi)
      #pragma unroll
      for (int ks = 0; ks < 2; ++ks)
        afrg[mi][ks] = RD(0, 0, wm, mi * 16 + lr, ks * 64 + lg * 16);
    STAGE(1, 1, 0, tb);
    __builtin_amdgcn_s_barrier();
    __builtin_amdgcn_s_setprio(1);
    #pragma unroll
    for (int mi = 0; mi < 2; ++mi)
      #pragma unroll
      for (int nj = 0; nj < 4; ++nj)
        #pragma unroll
        for (int ks = 0; ks < 2; ++ks)
          acc[mi][nj] = __builtin_amdgcn_mfma_f32_16x16x32_bf16(afrg[mi][ks], bfrg[nj][ks], acc[mi][nj], 0, 0, 0);
    __builtin_amdgcn_s_setprio(0);
    __builtin_amdgcn_s_barrier();

    // ph2: A q2..q4 reads (d0 A fully read after this phase); stage b.BH1 -> d1
    #pragma unroll
    for (int mi = 2; mi < 8; ++mi)
      #pragma unroll
      for (int ks = 0; ks < 2; ++ks)
        afrg[mi][ks] = RD(0, 0, wm, mi * 16 + lr, ks * 64 + lg * 16);
    STAGE(1, 1, 1, tb);
    __builtin_amdgcn_s_barrier();
    __builtin_amdgcn_s_setprio(1);
    #pragma unroll
    for (int mi = 2; mi < 4; ++mi)
      #pragma unroll
      for (int nj = 0; nj < 4; ++nj)
        #pragma unroll
        for (int ks = 0; ks < 2; ++ks)
          acc[mi][nj] = __builtin_amdgcn_mfma_f32_16x16x32_bf16(afrg[mi][ks], bfrg[nj][ks], acc[mi][nj], 0, 0, 0);
    __builtin_amdgcn_s_setprio(0);
    __builtin_amdgcn_s_barrier();

    // ph3: stage a'.AH0 -> d0 (d0 free: all reads done by ph2 barrier)
    STAGE(0, 0, 0, tn0);
    __builtin_amdgcn_s_barrier();
    __builtin_amdgcn_s_setprio(1);
    #pragma unroll
    for (int mi = 4; mi < 6; ++mi)
      #pragma unroll
      for (int nj = 0; nj < 4; ++nj)
        #pragma unroll
        for (int ks = 0; ks < 2; ++ks)
          acc[mi][nj] = __builtin_amdgcn_mfma_f32_16x16x32_bf16(afrg[mi][ks], bfrg[nj][ks], acc[mi][nj], 0, 0, 0);
    __builtin_amdgcn_s_setprio(0);
    __builtin_amdgcn_s_barrier();

    // ph4: stage a'.AH1 -> d0; counted vmcnt(4) => tile b fully landed
    STAGE(0, 0, 1, tn0);
    __builtin_amdgcn_s_barrier();
    __builtin_amdgcn_s_setprio(1);
    #pragma unroll
    for (int mi = 6; mi < 8; ++mi)
      #pragma unroll
      for (int nj = 0; nj < 4; ++nj)
        #pragma unroll
        for (int ks = 0; ks < 2; ++ks)
          acc[mi][nj] = __builtin_amdgcn_mfma_f32_16x16x32_bf16(afrg[mi][ks], bfrg[nj][ks], acc[mi][nj], 0, 0, 0);
    __builtin_amdgcn_s_setprio(0);
    asm volatile("s_waitcnt vmcnt(4)" ::: "memory");
    __builtin_amdgcn_s_barrier();

    // ================= K-tile b = 2*it+1, dbuf 1 =================
    // ph5: all B frags + A q1 from d1; stage a'.BH0 -> d0
    #pragma unroll
    for (int nj = 0; nj < 4; ++nj)
      #pragma unroll
      for (int ks = 0; ks < 2; ++ks)
        bfrg[nj][ks] = RD(1, 1, wn >> 1, brow + nj * 16 + lr, ks * 64 + lg * 16);
    #pragma unroll
    for (int mi = 0; mi < 2; ++mi)
      #pragma unroll
      for (int ks = 0; ks < 2; ++ks)
        afrg[mi][ks] = RD(1, 0, wm, mi * 16 + lr, ks * 64 + lg * 16);
    STAGE(0, 1, 0, tn0);
    __builtin_amdgcn_s_barrier();
    __builtin_amdgcn_s_setprio(1);
    #pragma unroll
    for (int mi = 0; mi < 2; ++mi)
      #pragma unroll
      for (int nj = 0; nj < 4; ++nj)
        #pragma unroll
        for (int ks = 0; ks < 2; ++ks)
          acc[mi][nj] = __builtin_amdgcn_mfma_f32_16x16x32_bf16(afrg[mi][ks], bfrg[nj][ks], acc[mi][nj], 0, 0, 0);
    __builtin_amdgcn_s_setprio(0);
    __builtin_amdgcn_s_barrier();

    // ph6: A q2..q4 from d1; stage a'.BH1 -> d0
    #pragma unroll
    for (int mi = 2; mi < 8; ++mi)
      #pragma unroll
      for (int ks = 0; ks < 2; ++ks)
        afrg[mi][ks] = RD(1, 0, wm, mi * 16 + lr, ks * 64 + lg * 16);
    STAGE(0, 1, 1, tn0);
    __builtin_amdgcn_s_barrier();
    __builtin_amdgcn_s_setprio(1);
    #pragma unroll
    for (int mi = 2; mi < 4; ++mi)
      #pragma unroll
      for (int nj = 0; nj < 4; ++nj)
        #pragma unroll
        for (int ks = 0; ks < 2; ++ks)
          acc[mi][nj] = __builtin_amdgcn_mfma_f32_16x16x32_bf16(afrg[mi][ks], bfrg[nj][ks], acc[mi][nj], 0, 0, 0);
    __builtin_amdgcn_s_setprio(0);
    __builtin_amdgcn_s_barrier();

    // ph7: stage b'.AH0 -> d1 (d1 free after ph6)
    STAGE(1, 0, 0, tn1);
    __builtin_amdgcn_s_barrier();
    __builtin_amdgcn_s_setprio(1);
    #pragma unroll
    for (int mi = 4; mi < 6; ++mi)
      #pragma unroll
      for (int nj = 0; nj < 4; ++nj)
        #pragma unroll
        for (int ks = 0; ks < 2; ++ks)
          acc[mi][nj] = __builtin_amdgcn_mfma_f32_16x16x32_bf16(afrg[mi][ks], bfrg[nj][ks], acc[mi][nj], 0, 0, 0);
    __builtin_amdgcn_s_setprio(0);
    __builtin_amdgcn_s_barrier();

    // ph8: stage b'.AH1 -> d1; vmcnt(4) => tile a' (= next d0) fully landed
    STAGE(1, 0, 1, tn1);
    __builtin_amdgcn_s_barrier();
    __builtin_amdgcn_s_setprio(1);
    #pragma unroll
    for (int mi = 6; mi < 8; ++mi)
      #pragma unroll
      for (int nj = 0; nj < 4; ++nj)
        #pragma unroll
        for (int ks = 0; ks < 2; ++ks)
          acc[mi][nj] = __builtin_amdgcn_mfma_f32_16x16x32_bf16(afrg[mi][ks], bfrg[nj][ks], acc[mi][nj], 0, 0, 0);
    __builtin_amdgcn_s_setprio(0);
    asm volatile("s_waitcnt vmcnt(4)" ::: "memory");
    __builtin_amdgcn_s_barrier();
  }

  // epilogue
  #pragma unroll
  for (int mi = 0; mi < 8; ++mi) {
    #pragma unroll
    for (int nj = 0; nj < 4; ++nj) {
      #pragma unroll
      for (int j = 0; j < 4; ++j) {
        int m = m0 + wm * 128 + mi * 16 + lg * 4 + j;
        int n = n0 + wn * 64 + nj * 16 + lr;
        float val = acc[mi][nj][j];
        if (EPI == 0) {
          C[(size_t)m * N + n] = val;
        } else {
          int which = n >> 11, cc = n & 2047;
          int h = cc >> 7, d = cc & 127;
          int b = m >> 11, t = m & 2047;
          unsigned short* dst = which == 0 ? qo : (which == 1 ? ko : vo);
          dst[(((size_t)(b * NH + h)) * T_SEQ + t) * HD + d] = f2bf(val);
        }
      }
    }
  }
}

// ---------------- RoPE in place on q (scaled by 1/sqrt(D)) and k ----------------
__global__ __launch_bounds__(256) void k_rope(unsigned short* __restrict__ q,
                                              unsigned short* __restrict__ k) {
  int i = blockIdx.x * 256 + threadIdx.x;   // over 32 * 2048 * 64
  int d = i & 63;
  int t = (i >> 6) & (T_SEQ - 1);
  int bh = i >> 17;
  float invf = exp2f((float)(-2 * d) * (13.287712379549449f / 128.f)); // 10000^(-2d/128)
  float ang = (float)t * invf;
  float c = cosf(ang), s = sinf(ang);
  size_t base = ((size_t)bh * T_SEQ + t) * HD + d;
  const float scale = 0.08838834764831845f;  // 1/sqrt(128)
  float q1 = bf2f(q[base]), q2 = bf2f(q[base + 64]);
  q[base]      = f2bf((q1 * c - q2 * s) * scale);
  q[base + 64] = f2bf((q2 * c + q1 * s) * scale);
  float k1 = bf2f(k[base]), k2 = bf2f(k[base + 64]);
  k[base]      = f2bf(k1 * c - k2 * s);
  k[base + 64] = f2bf(k2 * c + k1 * s);
}

// ---------------- bf16 transpose per (b,h): (T,D) -> (D,T) ----------------
__global__ __launch_bounds__(256) void k_transpose_v(const unsigned short* __restrict__ in,
                                                     unsigned short* __restrict__ out) {
  __shared__ unsigned short tile[32][33];
  int bh = blockIdx.z;
  int t0 = blockIdx.x * 32, d0 = blockIdx.y * 32;
  int tx = threadIdx.x & 31, ty = threadIdx.x >> 5;
  const unsigned short* src = in + (size_t)bh * T_SEQ * HD;
  unsigned short* dst = out + (size_t)bh * HD * T_SEQ;
  #pragma unroll
  for (int r = ty; r < 32; r += 8)
    tile[r][tx] = src[(size_t)(t0 + r) * HD + d0 + tx];
  __syncthreads();
  #pragma unroll
  for (int r = ty; r < 32; r += 8)
    dst[(size_t)(d0 + r) * T_SEQ + t0 + tx] = tile[tx][r];
}

// ---------------- causal flash attention (LPT order + reg-prefetch pipeline) ----------------
// Q,K: (B*H, T, D) bf16 (q pre-scaled).  Vt: (B*H, D, T) bf16.  Y: (B, T, C) bf16.
__global__ __launch_bounds__(256) void k_attn(const unsigned short* __restrict__ Q,
                                              const unsigned short* __restrict__ K,
                                              const unsigned short* __restrict__ Vt,
                                              unsigned short* __restrict__ Y) {
  __shared__ __align__(16) unsigned short Ks[64 * 128];   // XOR-swizzled
  __shared__ __align__(16) unsigned short Vs[128 * 64];   // XOR-swizzled
  __shared__ __align__(16) unsigned short Ps[64 * 80];    // padded rows (160B)
  const int bh = blockIdx.x;                    // fast dim: heads spread over XCDs
  const int qt = (T_SEQ / 64 - 1) - blockIdx.y; // heavy Q-tiles dispatch first (LPT)
  const int b = bh >> 4, h = bh & 15;
  const int tid = threadIdx.x, wave = tid >> 6, lane = tid & 63;
  const int lr = lane & 15, lg = lane >> 4;
  const int q0 = qt * 64;
  const unsigned short* Qb = Q + (size_t)bh * T_SEQ * HD;
  const unsigned short* Kb = K + (size_t)bh * T_SEQ * HD;
  const unsigned short* Vb = Vt + (size_t)bh * HD * T_SEQ;

  // per-thread staging geometry (constant across iterations)
  int rkA[4], okA[4], rvA[4], ovA[4], bkA[4], bvA[4];
  #pragma unroll
  for (int it = 0; it < 4; ++it) {
    int c = it * 256 + tid;
    rkA[it] = c >> 4; okA[it] = (c & 15) * 8;
    bkA[it] = (rkA[it] * 256 + (c & 15) * 16) ^ ((rkA[it] & 7) << 4);
    rvA[it] = c >> 3; ovA[it] = (c & 7) * 8;
    bvA[it] = (rvA[it] * 128 + (c & 7) * 16) ^ ((rvA[it] & 7) << 4);
  }

  // hoist Q fragments: wave's 16 rows, 4 K-slices of 32
  bf16x8 qf[4];
  #pragma unroll
  for (int kk = 0; kk < 4; ++kk)
    qf[kk] = *(const bf16x8*)(Qb + (size_t)(q0 + wave * 16 + lr) * HD + kk * 32 + lg * 8);

  const f32x4 fzero = {0.f, 0.f, 0.f, 0.f};
  f32x4 oacc[8];
  #pragma unroll
  for (int nd = 0; nd < 8; ++nd) oacc[nd] = fzero;
  float mrow[4], lrow[4];
  #pragma unroll
  for (int j = 0; j < 4; ++j) { mrow[j] = -1e30f; lrow[j] = 0.f; }

  // prologue: prefetch tile 0 into registers
  bf16x8 kst[4], vst[4];
  #pragma unroll
  for (int it = 0; it < 4; ++it) {
    kst[it] = *(const bf16x8*)(Kb + (size_t)rkA[it] * HD + okA[it]);
    vst[it] = *(const bf16x8*)(Vb + (size_t)rvA[it] * T_SEQ + ovA[it]);
  }

  for (int jt = 0; jt <= qt; ++jt) {
    const int tk0 = jt * 64;
    __syncthreads();   // previous iteration's LDS reads done
    // write staged regs -> LDS (swizzled)
    #pragma unroll
    for (int it = 0; it < 4; ++it) {
      *(bf16x8*)((char*)Ks + bkA[it]) = kst[it];
      *(bf16x8*)((char*)Vs + bvA[it]) = vst[it];
    }
    // issue next tile's loads; they fly under this tile's compute
    if (jt < qt) {
      const int nk0 = tk0 + 64;
      #pragma unroll
      for (int it = 0; it < 4; ++it) {
        kst[it] = *(const bf16x8*)(Kb + (size_t)(nk0 + rkA[it]) * HD + okA[it]);
        vst[it] = *(const bf16x8*)(Vb + (size_t)rvA[it] * T_SEQ + nk0 + ovA[it]);
      }
    }
    __syncthreads();   // LDS tile ready

    // S = Q K^T  (each wave: its 16 rows x 64 cols)
    f32x4 sacc[4];
    #pragma unroll
    for (int nr = 0; nr < 4; ++nr) sacc[nr] = fzero;
    #pragma unroll
    for (int nr = 0; nr < 4; ++nr) {
      #pragma unroll
      for (int kk = 0; kk < 4; ++kk) {
        int row = nr * 16 + lr;
        int byte = (row * 256 + kk * 64 + lg * 16) ^ ((row & 7) << 4);
        bf16x8 kf = *(const bf16x8*)((char*)Ks + byte);
        sacc[nr] = __builtin_amdgcn_mfma_f32_16x16x32_bf16(qf[kk], kf, sacc[nr], 0, 0, 0);
      }
    }

    if (jt == qt) {  // causal mask on diagonal tile
      #pragma unroll
      for (int nr = 0; nr < 4; ++nr)
        #pragma unroll
        for (int j = 0; j < 4; ++j) {
          int qg = q0 + wave * 16 + lg * 4 + j;
          int cg = tk0 + nr * 16 + lr;
          if (cg > qg) sacc[nr][j] = -1e30f;
        }
    }

    // online softmax (rows distributed: row = lg*4+j, 16 lanes share a row)
    float oscale[4];
    #pragma unroll
    for (int j = 0; j < 4; ++j) {
      float tmax = fmaxf(fmaxf(sacc[0][j], sacc[1][j]), fmaxf(sacc[2][j], sacc[3][j]));
      #pragma unroll
      for (int m = 1; m <= 8; m <<= 1) tmax = fmaxf(tmax, __shfl_xor(tmax, m));
      float mnew = fmaxf(mrow[j], tmax);
      oscale[j] = __expf(mrow[j] - mnew);
      float rsum = 0.f;
      #pragma unroll
      for (int nr = 0; nr < 4; ++nr) {
        float p = __expf(sacc[nr][j] - mnew);
        Ps[(wave * 16 + lg * 4 + j) * 80 + nr * 16 + lr] = f2bf(p);
        rsum += p;
      }
      #pragma unroll
      for (int m = 1; m <= 8; m <<= 1) rsum += __shfl_xor(rsum, m);
      lrow[j] = lrow[j] * oscale[j] + rsum;
      mrow[j] = mnew;
    }
    #pragma unroll
    for (int nd = 0; nd < 8; ++nd)
      #pragma unroll
      for (int j = 0; j < 4; ++j) oacc[nd][j] *= oscale[j];

    // PV: O += P * V   (P rows are wave-local in LDS; DS ops are in-order per wave)
    bf16x8 pf[2];
    #pragma unroll
    for (int kk = 0; kk < 2; ++kk)
      pf[kk] = *(const bf16x8*)(Ps + (wave * 16 + lr) * 80 + kk * 32 + lg * 8);
    #pragma unroll
    for (int nd = 0; nd < 8; ++nd) {
      #pragma unroll
      for (int kk = 0; kk < 2; ++kk) {
        int row = nd * 16 + lr;
        int byte = (row * 128 + kk * 64 + lg * 16) ^ ((row & 7) << 4);
        bf16x8 vf = *(const bf16x8*)((char*)Vs + byte);
        oacc[nd] = __builtin_amdgcn_mfma_f32_16x16x32_bf16(pf[kk], vf, oacc[nd], 0, 0, 0);
      }
    }
  }

  // epilogue: O / l -> Y (B,T,C)
  #pragma unroll
  for (int j = 0; j < 4; ++j) {
    float inv = 1.f / lrow[j];
    int qg = q0 + wave * 16 + lg * 4 + j;
    size_t base = ((size_t)b * T_SEQ + qg) * CC + h * HD;
    #pragma unroll
    for (int nd = 0; nd < 8; ++nd)
      Y[base + nd * 16 + lr] = f2bf(oacc[nd][j] * inv);
  }
}

extern "C" void kernel_launch(void* const* d_in, const int* in_sizes, int n_in,
                              void* d_out, int out_size, void* d_ws, size_t ws_size,
                              hipStream_t stream) {
  const float* x     = (const float*)d_in[0];
  const float* Wqkv  = (const float*)d_in[1];
  const float* Wproj = (const float*)d_in[2];
  float* out = (float*)d_out;
  char* ws = (char*)d_ws;
  const size_t MB = 1024 * 1024;
  unsigned short* WqkvT  = (unsigned short*)(ws + 0);        // 24MB; dead after GEMM1
  unsigned short* vt     = (unsigned short*)(ws + 0);        // 16MB, aliases WqkvT
  unsigned short* WprojT = (unsigned short*)(ws + 24 * MB);  // 8MB
  unsigned short* xb     = (unsigned short*)(ws + 32 * MB);  // 16MB; dead after GEMM1
  unsigned short* y      = xb;                               // aliases xb
  unsigned short* q      = (unsigned short*)(ws + 48 * MB);  // 16MB
  unsigned short* k      = (unsigned short*)(ws + 64 * MB);  // 16MB
  unsigned short* v      = (unsigned short*)(ws + 80 * MB);  // 16MB  (total 96MB)

  k_transpose_cvt<<<dim3(CC / 32, N3 / 32), 256, 0, stream>>>(Wqkv, WqkvT, CC, N3);
  k_transpose_cvt<<<dim3(CC / 32, CC / 32), 256, 0, stream>>>(Wproj, WprojT, CC, CC);
  k_cvt<<<(MM * CC / 4) / 256, 256, 0, stream>>>(x, xb, MM * CC / 4);
  k_gemm8<1><<<dim3(MM / 256, N3 / 256), 512, 131072, stream>>>(xb, WqkvT, nullptr, q, k, v, MM, N3, CC);
  k_rope<<<(32 * T_SEQ * 64) / 256, 256, 0, stream>>>(q, k);
  k_transpose_v<<<dim3(T_SEQ / 32, HD / 32, 32), 256, 0, stream>>>(v, vt);
  k_attn<<<dim3(32, T_SEQ / 64), 256, 0, stream>>>(q, k, vt, y);
  k_gemm8<0><<<dim3(MM / 256, CC / 256), 512, 131072, stream>>>(y, WprojT, out, nullptr, nullptr, nullptr, MM, CC, CC);
}

// Round 4
// 317.672 us; speedup vs baseline: 1.3386x; 1.3386x over previous
//
#include <hip/hip_runtime.h>
#include <stdint.h>

#define T_SEQ 2048
#define NH 16
#define HD 128
#define CC 2048
#define N3 6144
#define MM 4096   // B*T

typedef short bf16x8 __attribute__((ext_vector_type(8)));
typedef float f32x4 __attribute__((ext_vector_type(4)));

__device__ __forceinline__ unsigned short f2bf(float f) {
  unsigned int u = __float_as_uint(f);
  u += 0x7FFF + ((u >> 16) & 1);   // RNE
  return (unsigned short)(u >> 16);
}
__device__ __forceinline__ float bf2f(unsigned short h) {
  return __uint_as_float(((unsigned int)h) << 16);
}

// ---------------- transpose + fp32->bf16 convert: out[n][k] = in[k][n] ----------------
__global__ __launch_bounds__(256) void k_transpose_cvt(const float* __restrict__ in,
                                                       unsigned short* __restrict__ out,
                                                       int K, int N) {
  __shared__ float tile[32][33];
  int k0 = blockIdx.x * 32;
  int n0 = blockIdx.y * 32;
  int tx = threadIdx.x & 31, ty = threadIdx.x >> 5;   // ty 0..7
  #pragma unroll
  for (int r = ty; r < 32; r += 8)
    tile[r][tx] = in[(size_t)(k0 + r) * N + n0 + tx];
  __syncthreads();
  #pragma unroll
  for (int r = ty; r < 32; r += 8)
    out[(size_t)(n0 + r) * K + k0 + tx] = f2bf(tile[tx][r]);
}

// ---------------- fp32 -> bf16 elementwise (x) ----------------
__global__ __launch_bounds__(256) void k_cvt(const float* __restrict__ in,
                                             unsigned short* __restrict__ out, int n4) {
  int i = blockIdx.x * 256 + threadIdx.x;
  if (i >= n4) return;
  float4 v = ((const float4*)in)[i];
  ushort4 o;
  o.x = f2bf(v.x); o.y = f2bf(v.y); o.z = f2bf(v.z); o.w = f2bf(v.w);
  ((ushort4*)out)[i] = o;
}

// ---------------- bf16 GEMM, m97 structure (for GEMM2): C[M,N] = A[M,K] * Bt[N,K]^T ------
__global__ __launch_bounds__(256) void k_gemm(const unsigned short* __restrict__ A,
                                              const unsigned short* __restrict__ Bt,
                                              float* __restrict__ C,
                                              int M, int N, int K) {
  __shared__ __align__(16) unsigned short As[128 * 32];
  __shared__ __align__(16) unsigned short Bs[128 * 32];
  const int tid = threadIdx.x;
  const int wave = tid >> 6, lane = tid & 63;
  const int lr = lane & 15, lg = lane >> 4;
  const int m0 = blockIdx.x * 128, n0 = blockIdx.y * 128;
  const int wm = (wave >> 1) * 64, wn = (wave & 1) * 64;
  const f32x4 fzero = {0.f, 0.f, 0.f, 0.f};
  f32x4 acc[4][4];
  #pragma unroll
  for (int a = 0; a < 4; ++a)
    #pragma unroll
    for (int b = 0; b < 4; ++b) acc[a][b] = fzero;

  for (int k0 = 0; k0 < K; k0 += 32) {
    __syncthreads();
    #pragma unroll
    for (int it = 0; it < 2; ++it) {
      int c = it * 256 + wave * 64 + lane;
      int row = c >> 2, koff = (c & 3) * 8;
      int ldsoff = (it * 256 + wave * 64) * 16;
      __builtin_amdgcn_global_load_lds(
          (const __attribute__((address_space(1))) void*)(A + (size_t)(m0 + row) * K + k0 + koff),
          (__attribute__((address_space(3))) void*)((char*)As + ldsoff), 16, 0, 0);
      __builtin_amdgcn_global_load_lds(
          (const __attribute__((address_space(1))) void*)(Bt + (size_t)(n0 + row) * K + k0 + koff),
          (__attribute__((address_space(3))) void*)((char*)Bs + ldsoff), 16, 0, 0);
    }
    __syncthreads();
    bf16x8 af[4], bfr[4];
    #pragma unroll
    for (int mr = 0; mr < 4; ++mr)
      af[mr] = *(const bf16x8*)(As + (wm + mr * 16 + lr) * 32 + lg * 8);
    #pragma unroll
    for (int nr = 0; nr < 4; ++nr)
      bfr[nr] = *(const bf16x8*)(Bs + (wn + nr * 16 + lr) * 32 + lg * 8);
    #pragma unroll
    for (int mr = 0; mr < 4; ++mr)
      #pragma unroll
      for (int nr = 0; nr < 4; ++nr)
        acc[mr][nr] = __builtin_amdgcn_mfma_f32_16x16x32_bf16(af[mr], bfr[nr], acc[mr][nr], 0, 0, 0);
  }

  #pragma unroll
  for (int mr = 0; mr < 4; ++mr)
    #pragma unroll
    for (int nr = 0; nr < 4; ++nr)
      #pragma unroll
      for (int j = 0; j < 4; ++j) {
        int m = m0 + wm + mr * 16 + lg * 4 + j;
        int n = n0 + wn + nr * 16 + lr;
        C[(size_t)m * N + n] = acc[mr][nr][j];
      }
}

// ---------------- bf16 GEMM, 256x256 8-phase template (GEMM1): C = A[M,K] * Bt[N,K]^T ----
// 512 threads = 8 waves (2M x 4N). BK=64, 2 K-tiles/iteration, 128KB LDS.
// Swizzle: involutive XOR of byte bits [4:6] with row bits [0:2] (rows are 128B).
// Stage rotation (race-free): ph1/2: b.A->d1, ph3/4: a'.B->d0, ph5/6: a'.A->d0, ph7/8: b'.B->d1.
__global__ __launch_bounds__(512, 1) void k_gemm8(const unsigned short* __restrict__ A,
                                                  const unsigned short* __restrict__ Bt,
                                                  unsigned short* __restrict__ qo,
                                                  unsigned short* __restrict__ ko,
                                                  unsigned short* __restrict__ vo,
                                                  int M, int N, int K) {
  extern __shared__ __align__(16) char lds[];   // 131072 bytes
  const int tid = threadIdx.x;
  const int lane = tid & 63;
  const int lr = lane & 15, lg = lane >> 4;
  const int wave = tid >> 6;
  const int wm = wave >> 2, wn = wave & 3;
  // T1 bijective XCD swizzle (nwg % 8 == 0)
  const int nwg = gridDim.x;
  const int bid = blockIdx.x;
  const int wg = (nwg % 8 == 0) ? ((bid & 7) * (nwg >> 3) + (bid >> 3)) : bid;
  const int GX = M >> 8;
  const int m0 = (wg % GX) * 256, n0 = (wg / GX) * 256;
  const int NT = K >> 6;

  auto STAGE = [&](int d, int op, int h, int t) {
    const unsigned short* src = op ? Bt : A;
    const int r0 = (op ? n0 : m0) + h * 128;
    const int kc = t * 64;
    char* base = lds + ((((d << 1) | op) << 1 | h) << 14);
    #pragma unroll
    for (int l = 0; l < 2; ++l) {
      int p = (l * 512 + tid) * 16;
      int qq = p ^ (((p >> 7) & 7) << 4);
      const unsigned short* g = src + (size_t)(r0 + (qq >> 7)) * K + kc + ((qq & 127) >> 1);
      __builtin_amdgcn_global_load_lds(
          (const __attribute__((address_space(1))) void*)g,
          (__attribute__((address_space(3))) void*)(base + (l * 512 + (tid & 448)) * 16),
          16, 0, 0);
    }
  };
  auto RD = [&](int d, int op, int h, int row, int kb) -> bf16x8 {
    const char* base = lds + ((((d << 1) | op) << 1 | h) << 14);
    int p = row * 128 + kb;
    p ^= ((p >> 7) & 7) << 4;
    return *(const bf16x8*)(base + p);
  };

  f32x4 acc[8][4];
  #pragma unroll
  for (int i = 0; i < 8; ++i)
    #pragma unroll
    for (int j = 0; j < 4; ++j) acc[i][j] = (f32x4){0.f, 0.f, 0.f, 0.f};

  bf16x8 bfrg[4][2];

#define PHASE(D, MIB, READB, SD, SO, SH, ST, VM)                                         \
  {                                                                                      \
    if (READB) {                                                                         \
      _Pragma("unroll")                                                                  \
      for (int nj = 0; nj < 4; ++nj)                                                     \
        _Pragma("unroll")                                                                \
        for (int ks = 0; ks < 2; ++ks)                                                   \
          bfrg[nj][ks] = RD(D, 1, wn >> 1, (wn & 1) * 64 + nj * 16 + lr, ks * 64 + lg * 16); \
    }                                                                                    \
    bf16x8 af0[2], af1[2];                                                               \
    _Pragma("unroll")                                                                    \
    for (int ks = 0; ks < 2; ++ks) {                                                     \
      af0[ks] = RD(D, 0, wm, (MIB) * 16 + lr, ks * 64 + lg * 16);                        \
      af1[ks] = RD(D, 0, wm, (MIB + 1) * 16 + lr, ks * 64 + lg * 16);                    \
    }                                                                                    \
    STAGE(SD, SO, SH, ST);                                                               \
    __builtin_amdgcn_s_barrier();                                                        \
    asm volatile("s_waitcnt lgkmcnt(0)" ::: "memory");                                   \
    __builtin_amdgcn_s_setprio(1);                                                       \
    _Pragma("unroll")                                                                    \
    for (int nj = 0; nj < 4; ++nj)                                                       \
      _Pragma("unroll")                                                                  \
      for (int ks = 0; ks < 2; ++ks) {                                                   \
        acc[MIB][nj] = __builtin_amdgcn_mfma_f32_16x16x32_bf16(af0[ks], bfrg[nj][ks], acc[MIB][nj], 0, 0, 0);         \
        acc[MIB + 1][nj] = __builtin_amdgcn_mfma_f32_16x16x32_bf16(af1[ks], bfrg[nj][ks], acc[MIB + 1][nj], 0, 0, 0); \
      }                                                                                  \
    __builtin_amdgcn_s_setprio(0);                                                       \
    if (VM) asm volatile("s_waitcnt vmcnt(4)" ::: "memory");                             \
    __builtin_amdgcn_s_barrier();                                                        \
  }

  // prologue: tile0 -> d0 (A0,A1,B0,B1), tile1 B-halves -> d1
  const int t1 = NT > 1 ? 1 : 0;
  STAGE(0, 0, 0, 0); STAGE(0, 0, 1, 0); STAGE(0, 1, 0, 0); STAGE(0, 1, 1, 0);
  STAGE(1, 1, 0, t1); STAGE(1, 1, 1, t1);
  asm volatile("s_waitcnt vmcnt(4)" ::: "memory");   // tile0 fully landed
  __builtin_amdgcn_s_barrier();

  for (int it = 0; it < (NT >> 1); ++it) {
    const int tb  = 2 * it + 1;
    const int ta1 = min(2 * it + 2, NT - 1);
    const int tb1 = min(2 * it + 3, NT - 1);
    // K-tile a (d0): phases 1-4
    PHASE(0, 0, true,  1, 0, 0, tb,  false)   // + stage b.AH0 -> d1
    PHASE(0, 2, false, 1, 0, 1, tb,  false)   // + stage b.AH1 -> d1
    PHASE(0, 4, false, 0, 1, 0, ta1, false)   // + stage a'.BH0 -> d0
    PHASE(0, 6, false, 0, 1, 1, ta1, true )   // + stage a'.BH1 -> d0; vmcnt(4): b landed
    // K-tile b (d1): phases 5-8
    PHASE(1, 0, true,  0, 0, 0, ta1, false)   // + stage a'.AH0 -> d0
    PHASE(1, 2, false, 0, 0, 1, ta1, false)   // + stage a'.AH1 -> d0
    PHASE(1, 4, false, 1, 1, 0, tb1, false)   // + stage b'.BH0 -> d1
    PHASE(1, 6, false, 1, 1, 1, tb1, true )   // + stage b'.BH1 -> d1; vmcnt(4): a' landed
  }
#undef PHASE

  // epilogue: scatter bf16 into q/k/v (B,H,T,D)
  #pragma unroll
  for (int mi = 0; mi < 8; ++mi) {
    #pragma unroll
    for (int nj = 0; nj < 4; ++nj) {
      #pragma unroll
      for (int j = 0; j < 4; ++j) {
        int m = m0 + wm * 128 + mi * 16 + lg * 4 + j;
        int n = n0 + wn * 64 + nj * 16 + lr;
        float val = acc[mi][nj][j];
        int which = n >> 11, cc = n & 2047;
        int h = cc >> 7, d = cc & 127;
        int b = m >> 11, t = m & 2047;
        unsigned short* dst = which == 0 ? qo : (which == 1 ? ko : vo);
        dst[(((size_t)(b * NH + h)) * T_SEQ + t) * HD + d] = f2bf(val);
      }
    }
  }
}

// ---------------- RoPE in place on q (scaled by 1/sqrt(D)) and k ----------------
__global__ __launch_bounds__(256) void k_rope(unsigned short* __restrict__ q,
                                              unsigned short* __restrict__ k) {
  int i = blockIdx.x * 256 + threadIdx.x;   // over 32 * 2048 * 64
  int d = i & 63;
  int t = (i >> 6) & (T_SEQ - 1);
  int bh = i >> 17;
  float invf = exp2f((float)(-2 * d) * (13.287712379549449f / 128.f)); // 10000^(-2d/128)
  float ang = (float)t * invf;
  float c = cosf(ang), s = sinf(ang);
  size_t base = ((size_t)bh * T_SEQ + t) * HD + d;
  const float scale = 0.08838834764831845f;  // 1/sqrt(128)
  float q1 = bf2f(q[base]), q2 = bf2f(q[base + 64]);
  q[base]      = f2bf((q1 * c - q2 * s) * scale);
  q[base + 64] = f2bf((q2 * c + q1 * s) * scale);
  float k1 = bf2f(k[base]), k2 = bf2f(k[base + 64]);
  k[base]      = f2bf(k1 * c - k2 * s);
  k[base + 64] = f2bf(k2 * c + k1 * s);
}

// ---------------- bf16 transpose per (b,h): (T,D) -> (D,T) ----------------
__global__ __launch_bounds__(256) void k_transpose_v(const unsigned short* __restrict__ in,
                                                     unsigned short* __restrict__ out) {
  __shared__ unsigned short tile[32][33];
  int bh = blockIdx.z;
  int t0 = blockIdx.x * 32, d0 = blockIdx.y * 32;
  int tx = threadIdx.x & 31, ty = threadIdx.x >> 5;
  const unsigned short* src = in + (size_t)bh * T_SEQ * HD;
  unsigned short* dst = out + (size_t)bh * HD * T_SEQ;
  #pragma unroll
  for (int r = ty; r < 32; r += 8)
    tile[r][tx] = src[(size_t)(t0 + r) * HD + d0 + tx];
  __syncthreads();
  #pragma unroll
  for (int r = ty; r < 32; r += 8)
    dst[(size_t)(d0 + r) * T_SEQ + t0 + tx] = tile[tx][r];
}

// ---------------- causal flash attention (LPT order + reg-prefetch pipeline) ----------------
// Q,K: (B*H, T, D) bf16 (q pre-scaled).  Vt: (B*H, D, T) bf16.  Y: (B, T, C) bf16.
__global__ __launch_bounds__(256) void k_attn(const unsigned short* __restrict__ Q,
                                              const unsigned short* __restrict__ K,
                                              const unsigned short* __restrict__ Vt,
                                              unsigned short* __restrict__ Y) {
  __shared__ __align__(16) unsigned short Ks[64 * 128];   // XOR-swizzled
  __shared__ __align__(16) unsigned short Vs[128 * 64];   // XOR-swizzled
  __shared__ __align__(16) unsigned short Ps[64 * 80];    // padded rows (160B)
  const int bh = blockIdx.x;                    // fast dim: heads spread over XCDs
  const int qt = (T_SEQ / 64 - 1) - blockIdx.y; // heavy Q-tiles dispatch first (LPT)
  const int b = bh >> 4, h = bh & 15;
  const int tid = threadIdx.x, wave = tid >> 6, lane = tid & 63;
  const int lr = lane & 15, lg = lane >> 4;
  const int q0 = qt * 64;
  const unsigned short* Qb = Q + (size_t)bh * T_SEQ * HD;
  const unsigned short* Kb = K + (size_t)bh * T_SEQ * HD;
  const unsigned short* Vb = Vt + (size_t)bh * HD * T_SEQ;

  int rkA[4], okA[4], rvA[4], ovA[4], bkA[4], bvA[4];
  #pragma unroll
  for (int it = 0; it < 4; ++it) {
    int c = it * 256 + tid;
    rkA[it] = c >> 4; okA[it] = (c & 15) * 8;
    bkA[it] = (rkA[it] * 256 + (c & 15) * 16) ^ ((rkA[it] & 7) << 4);
    rvA[it] = c >> 3; ovA[it] = (c & 7) * 8;
    bvA[it] = (rvA[it] * 128 + (c & 7) * 16) ^ ((rvA[it] & 7) << 4);
  }

  bf16x8 qf[4];
  #pragma unroll
  for (int kk = 0; kk < 4; ++kk)
    qf[kk] = *(const bf16x8*)(Qb + (size_t)(q0 + wave * 16 + lr) * HD + kk * 32 + lg * 8);

  const f32x4 fzero = {0.f, 0.f, 0.f, 0.f};
  f32x4 oacc[8];
  #pragma unroll
  for (int nd = 0; nd < 8; ++nd) oacc[nd] = fzero;
  float mrow[4], lrow[4];
  #pragma unroll
  for (int j = 0; j < 4; ++j) { mrow[j] = -1e30f; lrow[j] = 0.f; }

  bf16x8 kst[4], vst[4];
  #pragma unroll
  for (int it = 0; it < 4; ++it) {
    kst[it] = *(const bf16x8*)(Kb + (size_t)rkA[it] * HD + okA[it]);
    vst[it] = *(const bf16x8*)(Vb + (size_t)rvA[it] * T_SEQ + ovA[it]);
  }

  for (int jt = 0; jt <= qt; ++jt) {
    const int tk0 = jt * 64;
    __syncthreads();
    #pragma unroll
    for (int it = 0; it < 4; ++it) {
      *(bf16x8*)((char*)Ks + bkA[it]) = kst[it];
      *(bf16x8*)((char*)Vs + bvA[it]) = vst[it];
    }
    if (jt < qt) {
      const int nk0 = tk0 + 64;
      #pragma unroll
      for (int it = 0; it < 4; ++it) {
        kst[it] = *(const bf16x8*)(Kb + (size_t)(nk0 + rkA[it]) * HD + okA[it]);
        vst[it] = *(const bf16x8*)(Vb + (size_t)rvA[it] * T_SEQ + nk0 + ovA[it]);
      }
    }
    __syncthreads();

    f32x4 sacc[4];
    #pragma unroll
    for (int nr = 0; nr < 4; ++nr) sacc[nr] = fzero;
    #pragma unroll
    for (int nr = 0; nr < 4; ++nr) {
      #pragma unroll
      for (int kk = 0; kk < 4; ++kk) {
        int row = nr * 16 + lr;
        int byte = (row * 256 + kk * 64 + lg * 16) ^ ((row & 7) << 4);
        bf16x8 kf = *(const bf16x8*)((char*)Ks + byte);
        sacc[nr] = __builtin_amdgcn_mfma_f32_16x16x32_bf16(qf[kk], kf, sacc[nr], 0, 0, 0);
      }
    }

    if (jt == qt) {
      #pragma unroll
      for (int nr = 0; nr < 4; ++nr)
        #pragma unroll
        for (int j = 0; j < 4; ++j) {
          int qg = q0 + wave * 16 + lg * 4 + j;
          int cg = tk0 + nr * 16 + lr;
          if (cg > qg) sacc[nr][j] = -1e30f;
        }
    }

    float oscale[4];
    #pragma unroll
    for (int j = 0; j < 4; ++j) {
      float tmax = fmaxf(fmaxf(sacc[0][j], sacc[1][j]), fmaxf(sacc[2][j], sacc[3][j]));
      #pragma unroll
      for (int m = 1; m <= 8; m <<= 1) tmax = fmaxf(tmax, __shfl_xor(tmax, m));
      float mnew = fmaxf(mrow[j], tmax);
      oscale[j] = __expf(mrow[j] - mnew);
      float rsum = 0.f;
      #pragma unroll
      for (int nr = 0; nr < 4; ++nr) {
        float p = __expf(sacc[nr][j] - mnew);
        Ps[(wave * 16 + lg * 4 + j) * 80 + nr * 16 + lr] = f2bf(p);
        rsum += p;
      }
      #pragma unroll
      for (int m = 1; m <= 8; m <<= 1) rsum += __shfl_xor(rsum, m);
      lrow[j] = lrow[j] * oscale[j] + rsum;
      mrow[j] = mnew;
    }
    #pragma unroll
    for (int nd = 0; nd < 8; ++nd)
      #pragma unroll
      for (int j = 0; j < 4; ++j) oacc[nd][j] *= oscale[j];

    bf16x8 pf[2];
    #pragma unroll
    for (int kk = 0; kk < 2; ++kk)
      pf[kk] = *(const bf16x8*)(Ps + (wave * 16 + lr) * 80 + kk * 32 + lg * 8);
    #pragma unroll
    for (int nd = 0; nd < 8; ++nd) {
      #pragma unroll
      for (int kk = 0; kk < 2; ++kk) {
        int row = nd * 16 + lr;
        int byte = (row * 128 + kk * 64 + lg * 16) ^ ((row & 7) << 4);
        bf16x8 vf = *(const bf16x8*)((char*)Vs + byte);
        oacc[nd] = __builtin_amdgcn_mfma_f32_16x16x32_bf16(pf[kk], vf, oacc[nd], 0, 0, 0);
      }
    }
  }

  #pragma unroll
  for (int j = 0; j < 4; ++j) {
    float inv = 1.f / lrow[j];
    int qg = q0 + wave * 16 + lg * 4 + j;
    size_t base = ((size_t)b * T_SEQ + qg) * CC + h * HD;
    #pragma unroll
    for (int nd = 0; nd < 8; ++nd)
      Y[base + nd * 16 + lr] = f2bf(oacc[nd][j] * inv);
  }
}

extern "C" void kernel_launch(void* const* d_in, const int* in_sizes, int n_in,
                              void* d_out, int out_size, void* d_ws, size_t ws_size,
                              hipStream_t stream) {
  const float* x     = (const float*)d_in[0];
  const float* Wqkv  = (const float*)d_in[1];
  const float* Wproj = (const float*)d_in[2];
  float* out = (float*)d_out;
  char* ws = (char*)d_ws;
  const size_t MB = 1024 * 1024;
  unsigned short* WqkvT  = (unsigned short*)(ws + 0);        // 24MB; dead after GEMM1
  unsigned short* vt     = (unsigned short*)(ws + 0);        // 16MB, aliases WqkvT
  unsigned short* WprojT = (unsigned short*)(ws + 24 * MB);  // 8MB
  unsigned short* xb     = (unsigned short*)(ws + 32 * MB);  // 16MB; dead after GEMM1
  unsigned short* y      = xb;                               // aliases xb
  unsigned short* q      = (unsigned short*)(ws + 48 * MB);  // 16MB
  unsigned short* k      = (unsigned short*)(ws + 64 * MB);  // 16MB
  unsigned short* v      = (unsigned short*)(ws + 80 * MB);  // 16MB  (total 96MB)

  k_transpose_cvt<<<dim3(CC / 32, N3 / 32), 256, 0, stream>>>(Wqkv, WqkvT, CC, N3);
  k_transpose_cvt<<<dim3(CC / 32, CC / 32), 256, 0, stream>>>(Wproj, WprojT, CC, CC);
  k_cvt<<<(MM * CC / 4) / 256, 256, 0, stream>>>(x, xb, MM * CC / 4);
  k_gemm8<<<dim3((MM / 256) * (N3 / 256)), 512, 131072, stream>>>(xb, WqkvT, q, k, v, MM, N3, CC);
  k_rope<<<(32 * T_SEQ * 64) / 256, 256, 0, stream>>>(q, k);
  k_transpose_v<<<dim3(T_SEQ / 32, HD / 32, 32), 256, 0, stream>>>(v, vt);
  k_attn<<<dim3(32, T_SEQ / 64), 256, 0, stream>>>(q, k, vt, y);
  k_gemm<<<dim3(MM / 128, CC / 128), 256, 0, stream>>>(y, WprojT, out, MM, CC, CC);
}

// Round 5
// 294.093 us; speedup vs baseline: 1.4459x; 1.0802x over previous
//
#include <hip/hip_runtime.h>
#include <stdint.h>

#define T_SEQ 2048
#define NH 16
#define HD 128
#define CC 2048
#define N3 6144
#define MM 4096   // B*T

typedef short bf16x8 __attribute__((ext_vector_type(8)));
typedef float f32x4 __attribute__((ext_vector_type(4)));

__device__ __forceinline__ unsigned short f2bf(float f) {
  unsigned int u = __float_as_uint(f);
  u += 0x7FFF + ((u >> 16) & 1);   // RNE
  return (unsigned short)(u >> 16);
}
__device__ __forceinline__ float bf2f(unsigned short h) {
  return __uint_as_float(((unsigned int)h) << 16);
}

// ---------------- transpose + fp32->bf16 convert: out[n][k] = in[k][n] ----------------
__global__ __launch_bounds__(256) void k_transpose_cvt(const float* __restrict__ in,
                                                       unsigned short* __restrict__ out,
                                                       int K, int N) {
  __shared__ float tile[32][33];
  int k0 = blockIdx.x * 32;
  int n0 = blockIdx.y * 32;
  int tx = threadIdx.x & 31, ty = threadIdx.x >> 5;   // ty 0..7
  #pragma unroll
  for (int r = ty; r < 32; r += 8)
    tile[r][tx] = in[(size_t)(k0 + r) * N + n0 + tx];
  __syncthreads();
  #pragma unroll
  for (int r = ty; r < 32; r += 8)
    out[(size_t)(n0 + r) * K + k0 + tx] = f2bf(tile[tx][r]);
}

// ---------------- fp32 -> bf16 elementwise (x) ----------------
__global__ __launch_bounds__(256) void k_cvt(const float* __restrict__ in,
                                             unsigned short* __restrict__ out, int n4) {
  int i = blockIdx.x * 256 + threadIdx.x;
  if (i >= n4) return;
  float4 v = ((const float4*)in)[i];
  ushort4 o;
  o.x = f2bf(v.x); o.y = f2bf(v.y); o.z = f2bf(v.z); o.w = f2bf(v.w);
  ((ushort4*)out)[i] = o;
}

// ---------------- bf16 GEMM, 8-phase template, BM=128, BN=NJ*64 -------------------------
// 512 threads = 8 waves (2M x 4N). BK=64, 2 K-tiles/iteration.
// LDS per dbuf: A unit (128x64 bf16 = 16KB) + BU=NJ/2 B units. NJ=6: 128KB, NJ=4: 96KB.
// Swizzle: involutive XOR of byte bits[4:6] with row bits[0:2] (rows = 128B).
// Stage plan (1 unit/phase): ph1: b.A->d1, ph2..: a'.B->d0, ph5: a'.A->d0, ph6..: b'.B->d1.
// vmcnt(2+BU*2-2=... ) = 6 (NJ=6) / 4 (NJ=4) at ph4 & ph8 only.
// EPI==0: fp32 C.  EPI==1: scatter bf16 into q/k/v (B,H,T,D).  MMAJ: XCD-chunk axis.
template<int NJ, int EPI, int MMAJ>
__global__ __launch_bounds__(512, 1) void k_gemm8(const unsigned short* __restrict__ A,
                                                  const unsigned short* __restrict__ Bt,
                                                  float* __restrict__ C,
                                                  unsigned short* __restrict__ qo,
                                                  unsigned short* __restrict__ ko,
                                                  unsigned short* __restrict__ vo,
                                                  int M, int N, int K) {
  constexpr int BU = NJ / 2;             // B units of 128 rows
  constexpr int DSTRIDE = (1 + BU) * 16384;
  extern __shared__ __align__(16) char lds[];
  const int tid = threadIdx.x;
  const int lane = tid & 63;
  const int lr = lane & 15, lg = lane >> 4;
  const int wave = tid >> 6;
  const int wm = wave >> 2, wn = wave & 3;
  // T1 bijective XCD swizzle (nwg % 8 == 0 here)
  const int nwg = gridDim.x;
  const int bid = blockIdx.x;
  const int wg = (bid & 7) * (nwg >> 3) + (bid >> 3);
  const int GX = M >> 7;
  const int GN = N / (NJ * 64);
  const int mt = MMAJ ? (wg % GX) : (wg / GN);
  const int nt = MMAJ ? (wg / GX) : (wg % GN);
  const int m0 = mt * 128, n0 = nt * NJ * 64;
  const int NT = K >> 6;

  // stage one 128x64 unit of tile t: op==0 -> A, op==1 -> B unit h
  auto STAGE = [&](int d, int op, int h, int t) {
    const unsigned short* src = op ? Bt : A;
    const int r0 = (op ? n0 + h * 128 : m0);
    const int kc = t * 64;
    char* base = lds + d * DSTRIDE + op * 16384 + h * 16384;
    #pragma unroll
    for (int l = 0; l < 2; ++l) {
      int p = (l * 512 + tid) * 16;
      int qq = p ^ (((p >> 7) & 7) << 4);
      const unsigned short* g = src + (size_t)(r0 + (qq >> 7)) * K + kc + ((qq & 127) >> 1);
      __builtin_amdgcn_global_load_lds(
          (const __attribute__((address_space(1))) void*)g,
          (__attribute__((address_space(3))) void*)(base + (l * 512 + (tid & 448)) * 16),
          16, 0, 0);
    }
  };
  // swizzled fragment read; row spans the whole region (A: 128 rows, B: BU*128 rows)
  auto RD = [&](int d, int op, int row, int kb) -> bf16x8 {
    const char* base = lds + d * DSTRIDE + op * 16384;
    int p = row * 128 + kb;
    p ^= ((p >> 7) & 7) << 4;
    return *(const bf16x8*)(base + p);
  };

  f32x4 acc[4][NJ];
  #pragma unroll
  for (int i = 0; i < 4; ++i)
    #pragma unroll
    for (int j = 0; j < NJ; ++j) acc[i][j] = (f32x4){0.f, 0.f, 0.f, 0.f};

  bf16x8 bfrg[NJ][2];

#define PHASE(D, MI, READB, DOST, SD, SO, SH, ST, VM)                                    \
  {                                                                                      \
    if (READB) {                                                                         \
      _Pragma("unroll")                                                                  \
      for (int nj = 0; nj < NJ; ++nj)                                                    \
        _Pragma("unroll")                                                                \
        for (int ks = 0; ks < 2; ++ks)                                                   \
          bfrg[nj][ks] = RD(D, 1, wn * NJ * 16 + nj * 16 + lr, ks * 64 + lg * 16);       \
    }                                                                                    \
    bf16x8 af[2];                                                                        \
    _Pragma("unroll")                                                                    \
    for (int ks = 0; ks < 2; ++ks)                                                       \
      af[ks] = RD(D, 0, wm * 64 + (MI) * 16 + lr, ks * 64 + lg * 16);                    \
    if (DOST) STAGE(SD, SO, SH, ST);                                                     \
    __builtin_amdgcn_s_barrier();                                                        \
    asm volatile("s_waitcnt lgkmcnt(0)" ::: "memory");                                   \
    __builtin_amdgcn_s_setprio(1);                                                       \
    _Pragma("unroll")                                                                    \
    for (int nj = 0; nj < NJ; ++nj)                                                      \
      _Pragma("unroll")                                                                  \
      for (int ks = 0; ks < 2; ++ks)                                                     \
        acc[MI][nj] = __builtin_amdgcn_mfma_f32_16x16x32_bf16(af[ks], bfrg[nj][ks], acc[MI][nj], 0, 0, 0); \
    __builtin_amdgcn_s_setprio(0);                                                       \
    if ((VM) == 6) asm volatile("s_waitcnt vmcnt(6)" ::: "memory");                      \
    if ((VM) == 4) asm volatile("s_waitcnt vmcnt(4)" ::: "memory");                      \
    __builtin_amdgcn_s_barrier();                                                        \
  }

  // prologue: tile0 full -> d0 (B units then A), tile1 B units -> d1 (t1.A staged in ph1)
  const int t1 = NT > 1 ? 1 : 0;
  #pragma unroll
  for (int h = 0; h < BU; ++h) STAGE(0, 1, h, 0);
  STAGE(0, 0, 0, 0);
  #pragma unroll
  for (int h = 0; h < BU; ++h) STAGE(1, 1, h, t1);
  if (NJ == 6) asm volatile("s_waitcnt vmcnt(6)" ::: "memory");
  else         asm volatile("s_waitcnt vmcnt(4)" ::: "memory");
  __builtin_amdgcn_s_barrier();

  for (int it = 0; it < (NT >> 1); ++it) {
    const int tb  = 2 * it + 1;
    const int ta1 = min(2 * it + 2, NT - 1);
    const int tb1 = min(2 * it + 3, NT - 1);
    if (NJ == 6) {
      // K-tile a (d0)
      PHASE(0, 0, true,  true, 1, 0, 0, tb,  -1)   // stage b.A  -> d1
      PHASE(0, 1, false, true, 0, 1, 0, ta1, -1)   // stage a'.B0 -> d0
      PHASE(0, 2, false, true, 0, 1, 1, ta1, -1)   // stage a'.B1 -> d0
      PHASE(0, 3, false, true, 0, 1, 2, ta1,  6)   // stage a'.B2 -> d0; vmcnt(6)
      // K-tile b (d1)
      PHASE(1, 0, true,  true, 0, 0, 0, ta1, -1)   // stage a'.A -> d0
      PHASE(1, 1, false, true, 1, 1, 0, tb1, -1)   // stage b'.B0 -> d1
      PHASE(1, 2, false, true, 1, 1, 1, tb1, -1)   // stage b'.B1 -> d1
      PHASE(1, 3, false, true, 1, 1, 2, tb1,  6)   // stage b'.B2 -> d1; vmcnt(6)
    } else {
      PHASE(0, 0, true,  true,  1, 0, 0, tb,  -1)  // stage b.A  -> d1
      PHASE(0, 1, false, true,  0, 1, 0, ta1, -1)  // stage a'.B0 -> d0
      PHASE(0, 2, false, true,  0, 1, 1, ta1, -1)  // stage a'.B1 -> d0
      PHASE(0, 3, false, false, 0, 0, 0, 0,    4)  // vmcnt(4)
      PHASE(1, 0, true,  true,  0, 0, 0, ta1, -1)  // stage a'.A -> d0
      PHASE(1, 1, false, true,  1, 1, 0, tb1, -1)  // stage b'.B0 -> d1
      PHASE(1, 2, false, true,  1, 1, 1, tb1, -1)  // stage b'.B1 -> d1
      PHASE(1, 3, false, false, 0, 0, 0, 0,    4)  // vmcnt(4)
    }
  }
#undef PHASE

  // epilogue
  #pragma unroll
  for (int mi = 0; mi < 4; ++mi) {
    #pragma unroll
    for (int nj = 0; nj < NJ; ++nj) {
      #pragma unroll
      for (int j = 0; j < 4; ++j) {
        int m = m0 + wm * 64 + mi * 16 + lg * 4 + j;
        int n = n0 + wn * NJ * 16 + nj * 16 + lr;
        float val = acc[mi][nj][j];
        if (EPI == 0) {
          C[(size_t)m * N + n] = val;
        } else {
          int which = n >> 11, cc = n & 2047;
          int h = cc >> 7, d = cc & 127;
          int b = m >> 11, t = m & 2047;
          unsigned short* dst = which == 0 ? qo : (which == 1 ? ko : vo);
          dst[(((size_t)(b * NH + h)) * T_SEQ + t) * HD + d] = f2bf(val);
        }
      }
    }
  }
}

// ---------------- RoPE in place on q (scaled by 1/sqrt(D)) and k ----------------
__global__ __launch_bounds__(256) void k_rope(unsigned short* __restrict__ q,
                                              unsigned short* __restrict__ k) {
  int i = blockIdx.x * 256 + threadIdx.x;   // over 32 * 2048 * 64
  int d = i & 63;
  int t = (i >> 6) & (T_SEQ - 1);
  int bh = i >> 17;
  float invf = exp2f((float)(-2 * d) * (13.287712379549449f / 128.f)); // 10000^(-2d/128)
  float ang = (float)t * invf;
  float c = cosf(ang), s = sinf(ang);
  size_t base = ((size_t)bh * T_SEQ + t) * HD + d;
  const float scale = 0.08838834764831845f;  // 1/sqrt(128)
  float q1 = bf2f(q[base]), q2 = bf2f(q[base + 64]);
  q[base]      = f2bf((q1 * c - q2 * s) * scale);
  q[base + 64] = f2bf((q2 * c + q1 * s) * scale);
  float k1 = bf2f(k[base]), k2 = bf2f(k[base + 64]);
  k[base]      = f2bf(k1 * c - k2 * s);
  k[base + 64] = f2bf(k2 * c + k1 * s);
}

// ---------------- bf16 transpose per (b,h): (T,D) -> (D,T) ----------------
__global__ __launch_bounds__(256) void k_transpose_v(const unsigned short* __restrict__ in,
                                                     unsigned short* __restrict__ out) {
  __shared__ unsigned short tile[32][33];
  int bh = blockIdx.z;
  int t0 = blockIdx.x * 32, d0 = blockIdx.y * 32;
  int tx = threadIdx.x & 31, ty = threadIdx.x >> 5;
  const unsigned short* src = in + (size_t)bh * T_SEQ * HD;
  unsigned short* dst = out + (size_t)bh * HD * T_SEQ;
  #pragma unroll
  for (int r = ty; r < 32; r += 8)
    tile[r][tx] = src[(size_t)(t0 + r) * HD + d0 + tx];
  __syncthreads();
  #pragma unroll
  for (int r = ty; r < 32; r += 8)
    dst[(size_t)(d0 + r) * T_SEQ + t0 + tx] = tile[tx][r];
}

// ---------------- causal flash attention (LPT order + reg-prefetch pipeline) ----------------
// Q,K: (B*H, T, D) bf16 (q pre-scaled).  Vt: (B*H, D, T) bf16.  Y: (B, T, C) bf16.
__global__ __launch_bounds__(256) void k_attn(const unsigned short* __restrict__ Q,
                                              const unsigned short* __restrict__ K,
                                              const unsigned short* __restrict__ Vt,
                                              unsigned short* __restrict__ Y) {
  __shared__ __align__(16) unsigned short Ks[64 * 128];   // XOR-swizzled
  __shared__ __align__(16) unsigned short Vs[128 * 64];   // XOR-swizzled
  __shared__ __align__(16) unsigned short Ps[64 * 80];    // padded rows (160B)
  const int bh = blockIdx.x;                    // fast dim: heads spread over XCDs
  const int qt = (T_SEQ / 64 - 1) - blockIdx.y; // heavy Q-tiles dispatch first (LPT)
  const int b = bh >> 4, h = bh & 15;
  const int tid = threadIdx.x, wave = tid >> 6, lane = tid & 63;
  const int lr = lane & 15, lg = lane >> 4;
  const int q0 = qt * 64;
  const unsigned short* Qb = Q + (size_t)bh * T_SEQ * HD;
  const unsigned short* Kb = K + (size_t)bh * T_SEQ * HD;
  const unsigned short* Vb = Vt + (size_t)bh * HD * T_SEQ;

  int rkA[4], okA[4], rvA[4], ovA[4], bkA[4], bvA[4];
  #pragma unroll
  for (int it = 0; it < 4; ++it) {
    int c = it * 256 + tid;
    rkA[it] = c >> 4; okA[it] = (c & 15) * 8;
    bkA[it] = (rkA[it] * 256 + (c & 15) * 16) ^ ((rkA[it] & 7) << 4);
    rvA[it] = c >> 3; ovA[it] = (c & 7) * 8;
    bvA[it] = (rvA[it] * 128 + (c & 7) * 16) ^ ((rvA[it] & 7) << 4);
  }

  bf16x8 qf[4];
  #pragma unroll
  for (int kk = 0; kk < 4; ++kk)
    qf[kk] = *(const bf16x8*)(Qb + (size_t)(q0 + wave * 16 + lr) * HD + kk * 32 + lg * 8);

  const f32x4 fzero = {0.f, 0.f, 0.f, 0.f};
  f32x4 oacc[8];
  #pragma unroll
  for (int nd = 0; nd < 8; ++nd) oacc[nd] = fzero;
  float mrow[4], lrow[4];
  #pragma unroll
  for (int j = 0; j < 4; ++j) { mrow[j] = -1e30f; lrow[j] = 0.f; }

  bf16x8 kst[4], vst[4];
  #pragma unroll
  for (int it = 0; it < 4; ++it) {
    kst[it] = *(const bf16x8*)(Kb + (size_t)rkA[it] * HD + okA[it]);
    vst[it] = *(const bf16x8*)(Vb + (size_t)rvA[it] * T_SEQ + ovA[it]);
  }

  for (int jt = 0; jt <= qt; ++jt) {
    const int tk0 = jt * 64;
    __syncthreads();
    #pragma unroll
    for (int it = 0; it < 4; ++it) {
      *(bf16x8*)((char*)Ks + bkA[it]) = kst[it];
      *(bf16x8*)((char*)Vs + bvA[it]) = vst[it];
    }
    if (jt < qt) {
      const int nk0 = tk0 + 64;
      #pragma unroll
      for (int it = 0; it < 4; ++it) {
        kst[it] = *(const bf16x8*)(Kb + (size_t)(nk0 + rkA[it]) * HD + okA[it]);
        vst[it] = *(const bf16x8*)(Vb + (size_t)rvA[it] * T_SEQ + nk0 + ovA[it]);
      }
    }
    __syncthreads();

    f32x4 sacc[4];
    #pragma unroll
    for (int nr = 0; nr < 4; ++nr) sacc[nr] = fzero;
    #pragma unroll
    for (int nr = 0; nr < 4; ++nr) {
      #pragma unroll
      for (int kk = 0; kk < 4; ++kk) {
        int row = nr * 16 + lr;
        int byte = (row * 256 + kk * 64 + lg * 16) ^ ((row & 7) << 4);
        bf16x8 kf = *(const bf16x8*)((char*)Ks + byte);
        sacc[nr] = __builtin_amdgcn_mfma_f32_16x16x32_bf16(qf[kk], kf, sacc[nr], 0, 0, 0);
      }
    }

    if (jt == qt) {
      #pragma unroll
      for (int nr = 0; nr < 4; ++nr)
        #pragma unroll
        for (int j = 0; j < 4; ++j) {
          int qg = q0 + wave * 16 + lg * 4 + j;
          int cg = tk0 + nr * 16 + lr;
          if (cg > qg) sacc[nr][j] = -1e30f;
        }
    }

    float oscale[4];
    #pragma unroll
    for (int j = 0; j < 4; ++j) {
      float tmax = fmaxf(fmaxf(sacc[0][j], sacc[1][j]), fmaxf(sacc[2][j], sacc[3][j]));
      #pragma unroll
      for (int m = 1; m <= 8; m <<= 1) tmax = fmaxf(tmax, __shfl_xor(tmax, m));
      float mnew = fmaxf(mrow[j], tmax);
      oscale[j] = __expf(mrow[j] - mnew);
      float rsum = 0.f;
      #pragma unroll
      for (int nr = 0; nr < 4; ++nr) {
        float p = __expf(sacc[nr][j] - mnew);
        Ps[(wave * 16 + lg * 4 + j) * 80 + nr * 16 + lr] = f2bf(p);
        rsum += p;
      }
      #pragma unroll
      for (int m = 1; m <= 8; m <<= 1) rsum += __shfl_xor(rsum, m);
      lrow[j] = lrow[j] * oscale[j] + rsum;
      mrow[j] = mnew;
    }
    #pragma unroll
    for (int nd = 0; nd < 8; ++nd)
      #pragma unroll
      for (int j = 0; j < 4; ++j) oacc[nd][j] *= oscale[j];

    bf16x8 pf[2];
    #pragma unroll
    for (int kk = 0; kk < 2; ++kk)
      pf[kk] = *(const bf16x8*)(Ps + (wave * 16 + lr) * 80 + kk * 32 + lg * 8);
    #pragma unroll
    for (int nd = 0; nd < 8; ++nd) {
      #pragma unroll
      for (int kk = 0; kk < 2; ++kk) {
        int row = nd * 16 + lr;
        int byte = (row * 128 + kk * 64 + lg * 16) ^ ((row & 7) << 4);
        bf16x8 vf = *(const bf16x8*)((char*)Vs + byte);
        oacc[nd] = __builtin_amdgcn_mfma_f32_16x16x32_bf16(pf[kk], vf, oacc[nd], 0, 0, 0);
      }
    }
  }

  #pragma unroll
  for (int j = 0; j < 4; ++j) {
    float inv = 1.f / lrow[j];
    int qg = q0 + wave * 16 + lg * 4 + j;
    size_t base = ((size_t)b * T_SEQ + qg) * CC + h * HD;
    #pragma unroll
    for (int nd = 0; nd < 8; ++nd)
      Y[base + nd * 16 + lr] = f2bf(oacc[nd][j] * inv);
  }
}

extern "C" void kernel_launch(void* const* d_in, const int* in_sizes, int n_in,
                              void* d_out, int out_size, void* d_ws, size_t ws_size,
                              hipStream_t stream) {
  const float* x     = (const float*)d_in[0];
  const float* Wqkv  = (const float*)d_in[1];
  const float* Wproj = (const float*)d_in[2];
  float* out = (float*)d_out;
  char* ws = (char*)d_ws;
  const size_t MB = 1024 * 1024;
  unsigned short* WqkvT  = (unsigned short*)(ws + 0);        // 24MB; dead after GEMM1
  unsigned short* vt     = (unsigned short*)(ws + 0);        // 16MB, aliases WqkvT
  unsigned short* WprojT = (unsigned short*)(ws + 24 * MB);  // 8MB
  unsigned short* xb     = (unsigned short*)(ws + 32 * MB);  // 16MB; dead after GEMM1
  unsigned short* y      = xb;                               // aliases xb
  unsigned short* q      = (unsigned short*)(ws + 48 * MB);  // 16MB
  unsigned short* k      = (unsigned short*)(ws + 64 * MB);  // 16MB
  unsigned short* v      = (unsigned short*)(ws + 80 * MB);  // 16MB  (total 96MB)

  k_transpose_cvt<<<dim3(CC / 32, N3 / 32), 256, 0, stream>>>(Wqkv, WqkvT, CC, N3);
  k_transpose_cvt<<<dim3(CC / 32, CC / 32), 256, 0, stream>>>(Wproj, WprojT, CC, CC);
  k_cvt<<<(MM * CC / 4) / 256, 256, 0, stream>>>(x, xb, MM * CC / 4);
  // GEMM1: 4096 x 6144 x 2048, BM=128 BN=384 -> grid 512 (exactly 2 gens), m-major chunks
  k_gemm8<6, 1, 1><<<dim3((MM / 128) * (N3 / 384)), 512, 131072, stream>>>(
      xb, WqkvT, nullptr, q, k, v, MM, N3, CC);
  k_rope<<<(32 * T_SEQ * 64) / 256, 256, 0, stream>>>(q, k);
  k_transpose_v<<<dim3(T_SEQ / 32, HD / 32, 32), 256, 0, stream>>>(v, vt);
  k_attn<<<dim3(32, T_SEQ / 64), 256, 0, stream>>>(q, k, vt, y);
  // GEMM2: 4096 x 2048 x 2048, BM=128 BN=256 -> grid 256 (exactly 1/CU), n-major chunks
  k_gemm8<4, 0, 0><<<dim3((MM / 128) * (CC / 256)), 512, 98304, stream>>>(
      y, WprojT, out, nullptr, nullptr, nullptr, MM, CC, CC);
}